// Round 1
// baseline (317.467 us; speedup 1.0000x reference)
//
#include <hip/hip_runtime.h>
#include <cmath>
#include <cfloat>

// Problem constants (fixed by setup_inputs: B=4, Q=100, K=17, H=W=128).
constexpr int NB = 4;
constexpr int NQ = 100;
constexpr int NK = 17;
constexpr int NH = 128;
constexpr int NW = 128;

constexpr float HUMAN_CONF = 0.7f;
constexpr float KP_CONF    = 0.5f;
constexpr float NMS_THR    = 0.5f;

// Output layout (flat float32, reference return order):
//   scores  [NB*NQ]          offset 0
//   boxes   [NB*NQ*4]        offset NB*NQ
//   kps     [NB*NQ*NK*3]     offset NB*NQ*5
//   keep    [NB*NQ]          offset NB*NQ*5 + NB*NQ*NK*3
constexpr int OFF_BOXES = NB * NQ;
constexpr int OFF_KPS   = NB * NQ * 5;
constexpr int OFF_KEEP  = NB * NQ * 5 + NB * NQ * NK * 3;

// ---------------- Kernel A: scores + boxes + per-batch greedy NMS ----------------
// One block per batch. 128 threads (Q=100 fits).
__global__ __launch_bounds__(128) void score_nms_kernel(
    const float* __restrict__ logits,   // [NB,NQ,2]
    const float* __restrict__ pboxes,   // [NB,NQ,4] cxcywh in [0,1]
    const int* __restrict__ img_h_p,    // scalar
    const int* __restrict__ img_w_p,    // scalar
    float* __restrict__ out,            // 22800 floats
    int* __restrict__ wkeep,            // ws: [NB*NQ]
    int* __restrict__ wbox)             // ws: [NB*NQ*4] boxes_int
{
    const int b = blockIdx.x;
    const int t = threadIdx.x;

    __shared__ float sbx[NQ][4];          // xyxy image coords, original order
    __shared__ float ssc[NQ];             // softmax max prob
    __shared__ unsigned char sval[NQ];    // valid flag
    __shared__ int   sorder[NQ];          // sorted pos -> original idx
    __shared__ float sortb[NQ][4];        // boxes in sorted order
    __shared__ float sarea[NQ];
    __shared__ unsigned char ssv[NQ];     // valid in sorted order
    __shared__ unsigned long long smask0[NQ], smask1[NQ]; // IoU>thr bitmask per sorted row
    __shared__ unsigned long long skmask[2];              // keep bits (sorted positions)

    const float iw = (float)img_w_p[0];
    const float ih = (float)img_h_p[0];

    if (t < NQ) {
        // softmax over 2 classes; score = max prob, label==0 iff l0 >= l1
        const float l0 = logits[(b * NQ + t) * 2 + 0];
        const float l1 = logits[(b * NQ + t) * 2 + 1];
        const float m  = fmaxf(l0, l1);
        const float e0 = expf(l0 - m);
        const float e1 = expf(l1 - m);
        const float score = fmaxf(e0, e1) / (e0 + e1);
        const bool  lab0  = (l0 >= l1);

        const float cx = pboxes[(b * NQ + t) * 4 + 0];
        const float cy = pboxes[(b * NQ + t) * 4 + 1];
        const float w  = pboxes[(b * NQ + t) * 4 + 2];
        const float h  = pboxes[(b * NQ + t) * 4 + 3];
        // (cx - 0.5w)*iw : 0.5*w exact, one rounded sub, *512 exact -> bit-stable
        sbx[t][0] = (cx - 0.5f * w) * iw;
        sbx[t][1] = (cy - 0.5f * h) * ih;
        sbx[t][2] = (cx + 0.5f * w) * iw;
        sbx[t][3] = (cy + 0.5f * h) * ih;
        ssc[t]  = score;
        sval[t] = (lab0 && score >= HUMAN_CONF) ? 1 : 0;
    }
    __syncthreads();

    // Rank by (key desc, index desc) == reverse of stable ascending argsort.
    if (t < NQ) {
        const float key = sval[t] ? ssc[t] : -INFINITY;
        int rank = 0;
        for (int j = 0; j < NQ; ++j) {
            const float kj = sval[j] ? ssc[j] : -INFINITY;
            if (kj > key || (kj == key && j > t)) rank++;
        }
        sorder[rank] = t;
    }
    __syncthreads();

    if (t < NQ) {
        const int oi = sorder[t];
        const float x1 = sbx[oi][0], y1 = sbx[oi][1], x2 = sbx[oi][2], y2 = sbx[oi][3];
        sortb[t][0] = x1; sortb[t][1] = y1; sortb[t][2] = x2; sortb[t][3] = y2;
        sarea[t] = fmaxf(x2 - x1, 0.0f) * fmaxf(y2 - y1, 0.0f);
        ssv[t]   = sval[oi];
    }
    __syncthreads();

    // Each sorted row t: bitmask over columns j with IoU(t,j) > thr.
    if (t < NQ) {
        unsigned long long m0 = 0ull, m1 = 0ull;
        const float ax1 = sortb[t][0], ay1 = sortb[t][1], ax2 = sortb[t][2], ay2 = sortb[t][3];
        const float aa = sarea[t];
        for (int j = 0; j < NQ; ++j) {
            const float lx = fmaxf(ax1, sortb[j][0]);
            const float ly = fmaxf(ay1, sortb[j][1]);
            const float rx = fminf(ax2, sortb[j][2]);
            const float ry = fminf(ay2, sortb[j][3]);
            const float wv = fmaxf(rx - lx, 0.0f);
            const float hv = fmaxf(ry - ly, 0.0f);
            const float inter = wv * hv;
            const float uni = aa + sarea[j] - inter;
            const float iou = inter / fmaxf(uni, 1e-9f);
            if (iou > NMS_THR) {
                if (j < 64) m0 |= 1ull << j; else m1 |= 1ull << (j - 64);
            }
        }
        smask0[t] = m0; smask1[t] = m1;
    }
    __syncthreads();

    // Serial greedy over bitmasks (100 scalar iterations, thread 0 only).
    if (t == 0) {
        unsigned long long sup0 = 0ull, sup1 = 0ull, k0 = 0ull, k1 = 0ull;
        for (int i = 0; i < NQ; ++i) {
            const bool sup = (i < 64) ? ((sup0 >> i) & 1ull) : ((sup1 >> (i - 64)) & 1ull);
            if (ssv[i] && !sup) {
                if (i < 64) k0 |= 1ull << i; else k1 |= 1ull << (i - 64);
                sup0 |= smask0[i];  // self/earlier bits harmless (already decided)
                sup1 |= smask1[i];
            }
        }
        skmask[0] = k0; skmask[1] = k1;
    }
    __syncthreads();

    // Write scores/boxes/keep outputs + workspace.
    if (t < NQ) {
        const int oi = sorder[t];
        const int kp = (t < 64) ? (int)((skmask[0] >> t) & 1ull)
                                : (int)((skmask[1] >> (t - 64)) & 1ull);
        const int gi = b * NQ + oi;

        out[gi] = ssc[oi] * (float)kp;

        const int bi0 = (int)sbx[oi][0];   // trunc toward zero == astype(int32)
        const int bi1 = (int)sbx[oi][1];
        const int bi2 = (int)sbx[oi][2];
        const int bi3 = (int)sbx[oi][3];
        out[OFF_BOXES + gi * 4 + 0] = (float)(bi0 * kp);
        out[OFF_BOXES + gi * 4 + 1] = (float)(bi1 * kp);
        out[OFF_BOXES + gi * 4 + 2] = (float)(bi2 * kp);
        out[OFF_BOXES + gi * 4 + 3] = (float)(bi3 * kp);

        out[OFF_KEEP + gi] = (float)kp;

        wkeep[gi] = kp;
        wbox[gi * 4 + 0] = bi0;
        wbox[gi * 4 + 1] = bi1;
        wbox[gi * 4 + 2] = bi2;
        wbox[gi * 4 + 3] = bi3;
    }
}

// ---------------- Kernel B: ROI keypoint argmax (kept boxes only) ----------------
// One block per (b,q). 256 threads = 4 waves; wave w handles keypoints w, w+4, ...
__global__ __launch_bounds__(256) void kps_kernel(
    const float* __restrict__ hm,       // [NB,NK,NH,NW]
    const int* __restrict__ wkeep,      // [NB*NQ]
    const int* __restrict__ wbox,       // [NB*NQ*4]
    const int* __restrict__ img_h_p,
    const int* __restrict__ img_w_p,
    float* __restrict__ out)
{
    const int blk = blockIdx.x;          // b*NQ + q
    const int tid = threadIdx.x;
    float* kout = out + OFF_KPS + blk * (NK * 3);

    if (wkeep[blk] == 0) {
        for (int i = tid; i < NK * 3; i += 256) kout[i] = 0.0f;
        return;
    }

    const float sx = (float)NW / (float)img_w_p[0];   // 0.25 exact for 512
    const float sy = (float)NH / (float)img_h_p[0];

    const int b0 = wbox[blk * 4 + 0];
    const int b1 = wbox[blk * 4 + 1];
    const int b2 = wbox[blk * 4 + 2];
    const int b3 = wbox[blk * 4 + 3];
    // int * 0.25f is exact; trunc toward zero matches astype(int32)
    const int x1 = max((int)((float)b0 * sx), 0);
    const int y1 = max((int)((float)b1 * sy), 0);
    const int x2 = min((int)((float)b2 * sx) + 1, NW);
    const int y2 = min((int)((float)b3 * sy) + 1, NH);

    if (!(x2 > x1 && y2 > y1)) {
        for (int i = tid; i < NK * 3; i += 256) kout[i] = 0.0f;
        return;
    }

    const int b    = blk / NQ;
    const int wave = tid >> 6;
    const int lane = tid & 63;

    for (int k = wave; k < NK; k += 4) {
        const float* base = hm + (size_t)(b * NK + k) * (NH * NW);
        float best = -INFINITY;
        int   bidx = 0x7fffffff;
        for (int y = y1; y < y2; ++y) {
            const float* row = base + y * NW;
            for (int x = x1 + lane; x < x2; x += 64) {
                const float v = row[x];
                // per-thread iteration order is increasing flat idx -> strict > keeps first
                if (v > best) { best = v; bidx = y * NW + x; }
            }
        }
        // 64-lane shuffle argmax reduce; tie -> smaller flat index (argmax semantics)
        for (int off = 32; off >= 1; off >>= 1) {
            const float ov = __shfl_down(best, off);
            const int   oi = __shfl_down(bidx, off);
            if (ov > best || (ov == best && oi < bidx)) { best = ov; bidx = oi; }
        }
        if (lane == 0) {
            const int col = bidx & (NW - 1);
            const int rw  = bidx >> 7;
            float conf = best;
            if (conf < KP_CONF) conf = 0.0f;
            kout[k * 3 + 0] = (float)col / sx;
            kout[k * 3 + 1] = (float)rw / sy;
            kout[k * 3 + 2] = conf;
        }
    }
}

extern "C" void kernel_launch(void* const* d_in, const int* in_sizes, int n_in,
                              void* d_out, int out_size, void* d_ws, size_t ws_size,
                              hipStream_t stream) {
    const float* logits = (const float*)d_in[0];   // [4,100,2]
    const float* pboxes = (const float*)d_in[1];   // [4,100,4]
    const float* hm     = (const float*)d_in[2];   // [4,17,128,128]
    const int*   img_h  = (const int*)d_in[3];
    const int*   img_w  = (const int*)d_in[4];
    float* out = (float*)d_out;

    int* wkeep = (int*)d_ws;               // [400]
    int* wbox  = wkeep + NB * NQ;          // [1600]

    score_nms_kernel<<<NB, 128, 0, stream>>>(logits, pboxes, img_h, img_w, out, wkeep, wbox);
    kps_kernel<<<NB * NQ, 256, 0, stream>>>(hm, wkeep, wbox, img_h, img_w, out);
}

// Round 2
// 175.384 us; speedup vs baseline: 1.8101x; 1.8101x over previous
//
#include <hip/hip_runtime.h>
#include <cmath>
#include <cfloat>

// Problem constants (fixed by setup_inputs: B=4, Q=100, K=17, H=W=128).
constexpr int NB = 4;
constexpr int NQ = 100;
constexpr int NK = 17;
constexpr int NH = 128;
constexpr int NW = 128;

constexpr float HUMAN_CONF = 0.7f;
constexpr float KP_CONF    = 0.5f;
constexpr float NMS_THR    = 0.5f;

// Output layout (flat float32, reference return order):
//   scores  [NB*NQ]          offset 0
//   boxes   [NB*NQ*4]        offset NB*NQ
//   kps     [NB*NQ*NK*3]     offset NB*NQ*5
//   keep    [NB*NQ]          offset NB*NQ*5 + NB*NQ*NK*3
constexpr int OFF_BOXES = NB * NQ;
constexpr int OFF_KPS   = NB * NQ * 5;
constexpr int OFF_KEEP  = NB * NQ * 5 + NB * NQ * NK * 3;

// ---------------- Kernel A: scores + boxes + per-batch greedy NMS ----------------
// One block per batch. 128 threads (Q=100 fits). Also zero-fills this batch's
// kps output slice (kernel B later overwrites kept entries only).
__global__ __launch_bounds__(128) void score_nms_kernel(
    const float* __restrict__ logits,   // [NB,NQ,2]
    const float* __restrict__ pboxes,   // [NB,NQ,4] cxcywh in [0,1]
    const int* __restrict__ img_h_p,    // scalar
    const int* __restrict__ img_w_p,    // scalar
    float* __restrict__ out,            // 22800 floats
    int* __restrict__ wkeep,            // ws: [NB*NQ]
    int* __restrict__ wbox)             // ws: [NB*NQ*4] boxes_int
{
    const int b = blockIdx.x;
    const int t = threadIdx.x;

    __shared__ float sbx[NQ][4];          // xyxy image coords, original order
    __shared__ float ssc[NQ];             // softmax max prob
    __shared__ unsigned char sval[NQ];    // valid flag
    __shared__ int   sorder[NQ];          // sorted pos -> original idx
    __shared__ float sortb[NQ][4];        // boxes in sorted order
    __shared__ float sarea[NQ];
    __shared__ unsigned char ssv[NQ];     // valid in sorted order
    __shared__ unsigned long long smask0[NQ], smask1[NQ]; // IoU>thr bitmask per sorted row
    __shared__ unsigned long long skmask[2];              // keep bits (sorted positions)

    // Zero-fill this batch's kps slice (NQ*NK*3 = 5100 floats).
    {
        float* kz = out + OFF_KPS + b * (NQ * NK * 3);
        for (int i = t; i < NQ * NK * 3; i += 128) kz[i] = 0.0f;
    }

    const float iw = (float)img_w_p[0];
    const float ih = (float)img_h_p[0];

    if (t < NQ) {
        // softmax over 2 classes; score = max prob, label==0 iff l0 >= l1
        const float l0 = logits[(b * NQ + t) * 2 + 0];
        const float l1 = logits[(b * NQ + t) * 2 + 1];
        const float m  = fmaxf(l0, l1);
        const float e0 = expf(l0 - m);
        const float e1 = expf(l1 - m);
        const float score = fmaxf(e0, e1) / (e0 + e1);
        const bool  lab0  = (l0 >= l1);

        const float cx = pboxes[(b * NQ + t) * 4 + 0];
        const float cy = pboxes[(b * NQ + t) * 4 + 1];
        const float w  = pboxes[(b * NQ + t) * 4 + 2];
        const float h  = pboxes[(b * NQ + t) * 4 + 3];
        sbx[t][0] = (cx - 0.5f * w) * iw;
        sbx[t][1] = (cy - 0.5f * h) * ih;
        sbx[t][2] = (cx + 0.5f * w) * iw;
        sbx[t][3] = (cy + 0.5f * h) * ih;
        ssc[t]  = score;
        sval[t] = (lab0 && score >= HUMAN_CONF) ? 1 : 0;
    }
    __syncthreads();

    // Rank by (key desc, index desc) == reverse of stable ascending argsort.
    if (t < NQ) {
        const float key = sval[t] ? ssc[t] : -INFINITY;
        int rank = 0;
        for (int j = 0; j < NQ; ++j) {
            const float kj = sval[j] ? ssc[j] : -INFINITY;
            if (kj > key || (kj == key && j > t)) rank++;
        }
        sorder[rank] = t;
    }
    __syncthreads();

    if (t < NQ) {
        const int oi = sorder[t];
        const float x1 = sbx[oi][0], y1 = sbx[oi][1], x2 = sbx[oi][2], y2 = sbx[oi][3];
        sortb[t][0] = x1; sortb[t][1] = y1; sortb[t][2] = x2; sortb[t][3] = y2;
        sarea[t] = fmaxf(x2 - x1, 0.0f) * fmaxf(y2 - y1, 0.0f);
        ssv[t]   = sval[oi];
    }
    __syncthreads();

    // Each sorted row t: bitmask over columns j with IoU(t,j) > thr.
    if (t < NQ) {
        unsigned long long m0 = 0ull, m1 = 0ull;
        const float ax1 = sortb[t][0], ay1 = sortb[t][1], ax2 = sortb[t][2], ay2 = sortb[t][3];
        const float aa = sarea[t];
        for (int j = 0; j < NQ; ++j) {
            const float lx = fmaxf(ax1, sortb[j][0]);
            const float ly = fmaxf(ay1, sortb[j][1]);
            const float rx = fminf(ax2, sortb[j][2]);
            const float ry = fminf(ay2, sortb[j][3]);
            const float wv = fmaxf(rx - lx, 0.0f);
            const float hv = fmaxf(ry - ly, 0.0f);
            const float inter = wv * hv;
            const float uni = aa + sarea[j] - inter;
            const float iou = inter / fmaxf(uni, 1e-9f);
            if (iou > NMS_THR) {
                if (j < 64) m0 |= 1ull << j; else m1 |= 1ull << (j - 64);
            }
        }
        smask0[t] = m0; smask1[t] = m1;
    }
    __syncthreads();

    // Serial greedy over bitmasks (thread 0). Sorted order puts all valid
    // boxes first, so we can break at the first invalid position.
    if (t == 0) {
        unsigned long long sup0 = 0ull, sup1 = 0ull, k0 = 0ull, k1 = 0ull;
        for (int i = 0; i < NQ; ++i) {
            if (!ssv[i]) break;   // all later positions invalid too
            const bool sup = (i < 64) ? ((sup0 >> i) & 1ull) : ((sup1 >> (i - 64)) & 1ull);
            if (!sup) {
                if (i < 64) k0 |= 1ull << i; else k1 |= 1ull << (i - 64);
                sup0 |= smask0[i];
                sup1 |= smask1[i];
            }
        }
        skmask[0] = k0; skmask[1] = k1;
    }
    __syncthreads();

    // Write scores/boxes/keep outputs + workspace.
    if (t < NQ) {
        const int oi = sorder[t];
        const int kp = (t < 64) ? (int)((skmask[0] >> t) & 1ull)
                                : (int)((skmask[1] >> (t - 64)) & 1ull);
        const int gi = b * NQ + oi;

        out[gi] = ssc[oi] * (float)kp;

        const int bi0 = (int)sbx[oi][0];   // trunc toward zero == astype(int32)
        const int bi1 = (int)sbx[oi][1];
        const int bi2 = (int)sbx[oi][2];
        const int bi3 = (int)sbx[oi][3];
        out[OFF_BOXES + gi * 4 + 0] = (float)(bi0 * kp);
        out[OFF_BOXES + gi * 4 + 1] = (float)(bi1 * kp);
        out[OFF_BOXES + gi * 4 + 2] = (float)(bi2 * kp);
        out[OFF_BOXES + gi * 4 + 3] = (float)(bi3 * kp);

        out[OFF_KEEP + gi] = (float)kp;

        wkeep[gi] = kp;
        wbox[gi * 4 + 0] = bi0;
        wbox[gi * 4 + 1] = bi1;
        wbox[gi * 4 + 2] = bi2;
        wbox[gi * 4 + 3] = bi3;
    }
}

// ---------------- Kernel B: ROI keypoint argmax via LDS-resident heatmap ----------------
// One block per (b,k): 68 blocks, 256 threads (4 waves). Stage the whole
// 128x128 heatmap into LDS once (each HBM line fetched exactly once), then
// each wave scans the ROIs of kept boxes q ≡ wave (mod 4) from LDS.
__global__ __launch_bounds__(256) void kps_kernel(
    const float* __restrict__ hm,       // [NB,NK,NH,NW]
    const int* __restrict__ wkeep,      // [NB*NQ]
    const int* __restrict__ wbox,       // [NB*NQ*4]
    const int* __restrict__ img_h_p,
    const int* __restrict__ img_w_p,
    float* __restrict__ out)
{
    __shared__ float shm[NH * NW];      // 64 KiB

    const int blk = blockIdx.x;          // b*NK + k
    const int b   = blk / NK;
    const int k   = blk - b * NK;
    const int tid = threadIdx.x;

    // Stage heatmap (b,k) -> LDS, coalesced float4 (16 iters/thread, independent).
    {
        const float4* src = (const float4*)(hm + (size_t)(b * NK + k) * (NH * NW));
        float4* dst = (float4*)shm;
        #pragma unroll
        for (int i = 0; i < (NH * NW / 4) / 256; ++i)
            dst[tid + i * 256] = src[tid + i * 256];
    }
    __syncthreads();

    const float sx = (float)NW / (float)img_w_p[0];   // 0.25 exact for 512
    const float sy = (float)NH / (float)img_h_p[0];

    const int wave = tid >> 6;
    const int lane = tid & 63;

    // Each wave handles q = wave, wave+4, ... independently (no block reduce).
    for (int q = wave; q < NQ; q += 4) {
        const int gi = b * NQ + q;
        if (wkeep[gi] == 0) continue;           // kps already zeroed by kernel A

        const int b0 = wbox[gi * 4 + 0];
        const int b1 = wbox[gi * 4 + 1];
        const int b2 = wbox[gi * 4 + 2];
        const int b3 = wbox[gi * 4 + 3];
        // int * 0.25f exact; trunc toward zero matches astype(int32)
        const int x1 = max((int)((float)b0 * sx), 0);
        const int y1 = max((int)((float)b1 * sy), 0);
        const int x2 = min((int)((float)b2 * sx) + 1, NW);
        const int y2 = min((int)((float)b3 * sy) + 1, NH);
        if (!(x2 > x1 && y2 > y1)) continue;    // stays zero

        float best = -INFINITY;
        int   bidx = 0x7fffffff;
        for (int y = y1; y < y2; ++y) {
            const float* row = shm + y * NW;
            for (int x = x1 + lane; x < x2; x += 64) {
                const float v = row[x];
                // per-thread visit order is increasing flat idx -> strict > keeps first
                if (v > best) { best = v; bidx = y * NW + x; }
            }
        }
        // 64-lane shuffle argmax reduce; tie -> smaller flat index (argmax semantics)
        for (int off = 32; off >= 1; off >>= 1) {
            const float ov = __shfl_down(best, off);
            const int   oi = __shfl_down(bidx, off);
            if (ov > best || (ov == best && oi < bidx)) { best = ov; bidx = oi; }
        }
        if (lane == 0) {
            const int col = bidx & (NW - 1);
            const int rw  = bidx >> 7;
            float conf = best;
            if (conf < KP_CONF) conf = 0.0f;
            float* kout = out + OFF_KPS + (size_t)gi * (NK * 3) + k * 3;
            kout[0] = (float)col / sx;
            kout[1] = (float)rw / sy;
            kout[2] = conf;
        }
    }
}

extern "C" void kernel_launch(void* const* d_in, const int* in_sizes, int n_in,
                              void* d_out, int out_size, void* d_ws, size_t ws_size,
                              hipStream_t stream) {
    const float* logits = (const float*)d_in[0];   // [4,100,2]
    const float* pboxes = (const float*)d_in[1];   // [4,100,4]
    const float* hm     = (const float*)d_in[2];   // [4,17,128,128]
    const int*   img_h  = (const int*)d_in[3];
    const int*   img_w  = (const int*)d_in[4];
    float* out = (float*)d_out;

    int* wkeep = (int*)d_ws;               // [400]
    int* wbox  = wkeep + NB * NQ;          // [1600]

    score_nms_kernel<<<NB, 128, 0, stream>>>(logits, pboxes, img_h, img_w, out, wkeep, wbox);
    kps_kernel<<<NB * NK, 256, 0, stream>>>(hm, wkeep, wbox, img_h, img_w, out);
}

// Round 3
// 110.623 us; speedup vs baseline: 2.8698x; 1.5854x over previous
//
#include <hip/hip_runtime.h>
#include <cmath>
#include <cfloat>

// Problem constants (fixed by setup_inputs: B=4, Q=100, K=17, H=W=128).
constexpr int NB = 4;
constexpr int NQ = 100;
constexpr int NK = 17;
constexpr int NH = 128;
constexpr int NW = 128;

constexpr float HUMAN_CONF = 0.7f;
constexpr float KP_CONF    = 0.5f;
constexpr float NMS_THR    = 0.5f;

// Output layout (flat float32, reference return order):
//   scores  [NB*NQ]          offset 0
//   boxes   [NB*NQ*4]        offset NB*NQ
//   kps     [NB*NQ*NK*3]     offset NB*NQ*5
//   keep    [NB*NQ]          offset NB*NQ*5 + NB*NQ*NK*3
constexpr int OFF_BOXES = NB * NQ;
constexpr int OFF_KPS   = NB * NQ * 5;
constexpr int OFF_KEEP  = NB * NQ * 5 + NB * NQ * NK * 3;

// ---------------- Kernel A: scores + boxes + per-batch greedy NMS ----------------
// One block per batch. 128 threads (Q=100 fits).
__global__ __launch_bounds__(128) void score_nms_kernel(
    const float* __restrict__ logits,   // [NB,NQ,2]
    const float* __restrict__ pboxes,   // [NB,NQ,4] cxcywh in [0,1]
    const int* __restrict__ img_h_p,    // scalar
    const int* __restrict__ img_w_p,    // scalar
    float* __restrict__ out,            // 22800 floats
    int* __restrict__ wkeep,            // ws: [NB*NQ]
    int* __restrict__ wbox)             // ws: [NB*NQ*4] boxes_int
{
    const int b = blockIdx.x;
    const int t = threadIdx.x;

    __shared__ float sbx[NQ][4];          // xyxy image coords, original order
    __shared__ float ssc[NQ];             // softmax max prob
    __shared__ unsigned char sval[NQ];    // valid flag
    __shared__ int   sorder[NQ];          // sorted pos -> original idx
    __shared__ float sortb[NQ][4];        // boxes in sorted order
    __shared__ float sarea[NQ];
    __shared__ unsigned char ssv[NQ];     // valid in sorted order
    __shared__ unsigned long long smask0[NQ], smask1[NQ]; // IoU>thr bitmask per sorted row
    __shared__ unsigned long long skmask[2];              // keep bits (sorted positions)

    const float iw = (float)img_w_p[0];
    const float ih = (float)img_h_p[0];

    if (t < NQ) {
        // softmax over 2 classes; score = max prob, label==0 iff l0 >= l1
        const float l0 = logits[(b * NQ + t) * 2 + 0];
        const float l1 = logits[(b * NQ + t) * 2 + 1];
        const float m  = fmaxf(l0, l1);
        const float e0 = expf(l0 - m);
        const float e1 = expf(l1 - m);
        const float score = fmaxf(e0, e1) / (e0 + e1);
        const bool  lab0  = (l0 >= l1);

        const float cx = pboxes[(b * NQ + t) * 4 + 0];
        const float cy = pboxes[(b * NQ + t) * 4 + 1];
        const float w  = pboxes[(b * NQ + t) * 4 + 2];
        const float h  = pboxes[(b * NQ + t) * 4 + 3];
        sbx[t][0] = (cx - 0.5f * w) * iw;
        sbx[t][1] = (cy - 0.5f * h) * ih;
        sbx[t][2] = (cx + 0.5f * w) * iw;
        sbx[t][3] = (cy + 0.5f * h) * ih;
        ssc[t]  = score;
        sval[t] = (lab0 && score >= HUMAN_CONF) ? 1 : 0;
    }
    __syncthreads();

    // Rank by (key desc, index desc) == reverse of stable ascending argsort.
    if (t < NQ) {
        const float key = sval[t] ? ssc[t] : -INFINITY;
        int rank = 0;
        for (int j = 0; j < NQ; ++j) {
            const float kj = sval[j] ? ssc[j] : -INFINITY;
            if (kj > key || (kj == key && j > t)) rank++;
        }
        sorder[rank] = t;
    }
    __syncthreads();

    if (t < NQ) {
        const int oi = sorder[t];
        const float x1 = sbx[oi][0], y1 = sbx[oi][1], x2 = sbx[oi][2], y2 = sbx[oi][3];
        sortb[t][0] = x1; sortb[t][1] = y1; sortb[t][2] = x2; sortb[t][3] = y2;
        sarea[t] = fmaxf(x2 - x1, 0.0f) * fmaxf(y2 - y1, 0.0f);
        ssv[t]   = sval[oi];
    }
    __syncthreads();

    // Each sorted row t: bitmask over columns j with IoU(t,j) > thr.
    if (t < NQ) {
        unsigned long long m0 = 0ull, m1 = 0ull;
        const float ax1 = sortb[t][0], ay1 = sortb[t][1], ax2 = sortb[t][2], ay2 = sortb[t][3];
        const float aa = sarea[t];
        for (int j = 0; j < NQ; ++j) {
            const float lx = fmaxf(ax1, sortb[j][0]);
            const float ly = fmaxf(ay1, sortb[j][1]);
            const float rx = fminf(ax2, sortb[j][2]);
            const float ry = fminf(ay2, sortb[j][3]);
            const float wv = fmaxf(rx - lx, 0.0f);
            const float hv = fmaxf(ry - ly, 0.0f);
            const float inter = wv * hv;
            const float uni = aa + sarea[j] - inter;
            const float iou = inter / fmaxf(uni, 1e-9f);
            if (iou > NMS_THR) {
                if (j < 64) m0 |= 1ull << j; else m1 |= 1ull << (j - 64);
            }
        }
        smask0[t] = m0; smask1[t] = m1;
    }
    __syncthreads();

    // Serial greedy over bitmasks (thread 0). Sorted order puts all valid
    // boxes first, so break at the first invalid position.
    if (t == 0) {
        unsigned long long sup0 = 0ull, sup1 = 0ull, k0 = 0ull, k1 = 0ull;
        for (int i = 0; i < NQ; ++i) {
            if (!ssv[i]) break;
            const bool sup = (i < 64) ? ((sup0 >> i) & 1ull) : ((sup1 >> (i - 64)) & 1ull);
            if (!sup) {
                if (i < 64) k0 |= 1ull << i; else k1 |= 1ull << (i - 64);
                sup0 |= smask0[i];
                sup1 |= smask1[i];
            }
        }
        skmask[0] = k0; skmask[1] = k1;
    }
    __syncthreads();

    // Write scores/boxes/keep outputs + workspace.
    if (t < NQ) {
        const int oi = sorder[t];
        const int kp = (t < 64) ? (int)((skmask[0] >> t) & 1ull)
                                : (int)((skmask[1] >> (t - 64)) & 1ull);
        const int gi = b * NQ + oi;

        out[gi] = ssc[oi] * (float)kp;

        const int bi0 = (int)sbx[oi][0];   // trunc toward zero == astype(int32)
        const int bi1 = (int)sbx[oi][1];
        const int bi2 = (int)sbx[oi][2];
        const int bi3 = (int)sbx[oi][3];
        out[OFF_BOXES + gi * 4 + 0] = (float)(bi0 * kp);
        out[OFF_BOXES + gi * 4 + 1] = (float)(bi1 * kp);
        out[OFF_BOXES + gi * 4 + 2] = (float)(bi2 * kp);
        out[OFF_BOXES + gi * 4 + 3] = (float)(bi3 * kp);

        out[OFF_KEEP + gi] = (float)kp;

        wkeep[gi] = kp;
        wbox[gi * 4 + 0] = bi0;
        wbox[gi * 4 + 1] = bi1;
        wbox[gi * 4 + 2] = bi2;
        wbox[gi * 4 + 3] = bi3;
    }
}

// ---------------- Kernel B: ROI keypoint argmax, one wave per (box, keypoint) ----------------
// Grid = NB*NQ*NK blocks of 64 threads. Non-kept blocks write their 3 zeros and
// exit (replaces the old bulk zero-fill). Kept blocks scan a FLATTENED ROI with
// a uniform trip count and 4 loads in flight per iteration (latency hiding both
// within the wave and across the ~1000 active co-resident waves).
__global__ __launch_bounds__(64) void kps_kernel(
    const float* __restrict__ hm,       // [NB,NK,NH,NW]
    const int* __restrict__ wkeep,      // [NB*NQ]
    const int* __restrict__ wbox,       // [NB*NQ*4]
    const int* __restrict__ img_h_p,
    const int* __restrict__ img_w_p,
    float* __restrict__ out)
{
    const int bb   = blockIdx.x;         // gi*NK + k
    const int gi   = bb / NK;
    const int k    = bb - gi * NK;
    const int lane = threadIdx.x;

    float* kout = out + OFF_KPS + (size_t)gi * (NK * 3) + k * 3;

    const float sx = (float)NW / (float)img_w_p[0];   // 0.25 exact for 512
    const float sy = (float)NH / (float)img_h_p[0];

    bool dead = (wkeep[gi] == 0);
    int x1 = 0, y1 = 0, x2 = 0, y2 = 0;
    if (!dead) {
        const int b0 = wbox[gi * 4 + 0];
        const int b1 = wbox[gi * 4 + 1];
        const int b2 = wbox[gi * 4 + 2];
        const int b3 = wbox[gi * 4 + 3];
        // int * 0.25f exact; trunc toward zero matches astype(int32)
        x1 = max((int)((float)b0 * sx), 0);
        y1 = max((int)((float)b1 * sy), 0);
        x2 = min((int)((float)b2 * sx) + 1, NW);
        y2 = min((int)((float)b3 * sy) + 1, NH);
        dead = !(x2 > x1 && y2 > y1);
    }
    if (dead) {
        if (lane < 3) kout[lane] = 0.0f;
        return;
    }

    const int b = gi / NQ;
    const float* __restrict__ base = hm + (size_t)(b * NK + k) * (NH * NW);

    const int w     = x2 - x1;                 // 1..128
    const int total = w * (y2 - y1);           // <= 16384
    // Granlund-Montgomery magic for floor(i/w): exact for i,w < 2^16.
    const unsigned M = (w > 1) ? (0xFFFFFFFFu / (unsigned)w + 1u) : 0u;

    float best = -INFINITY;
    int   bidx = 0x7fffffff;                   // global flat idx y*NW+x

    auto visit = [&](int i, float v) {
        // strict > keeps the earliest (smallest flat idx) occurrence
        const int y = (w == 1) ? i : (int)__umulhi((unsigned)i, M);
        const int g = (y1 + y) * NW + x1 + (i - y * w);
        if (v > best) { best = v; bidx = g; }
    };

    int i = lane;
    // 4-way: issue 4 independent loads, then compare in index order.
    for (; i + 192 < total; i += 256) {
        const int i0 = i, i1 = i + 64, i2 = i + 128, i3 = i + 192;
        const int yy0 = (w == 1) ? i0 : (int)__umulhi((unsigned)i0, M);
        const int yy1 = (w == 1) ? i1 : (int)__umulhi((unsigned)i1, M);
        const int yy2 = (w == 1) ? i2 : (int)__umulhi((unsigned)i2, M);
        const int yy3 = (w == 1) ? i3 : (int)__umulhi((unsigned)i3, M);
        const int g0 = (y1 + yy0) * NW + x1 + (i0 - yy0 * w);
        const int g1 = (y1 + yy1) * NW + x1 + (i1 - yy1 * w);
        const int g2 = (y1 + yy2) * NW + x1 + (i2 - yy2 * w);
        const int g3 = (y1 + yy3) * NW + x1 + (i3 - yy3 * w);
        const float v0 = base[g0];
        const float v1 = base[g1];
        const float v2 = base[g2];
        const float v3 = base[g3];
        if (v0 > best) { best = v0; bidx = g0; }
        if (v1 > best) { best = v1; bidx = g1; }
        if (v2 > best) { best = v2; bidx = g2; }
        if (v3 > best) { best = v3; bidx = g3; }
    }
    for (; i < total; i += 64) visit(i, base[(((w == 1) ? i : (int)__umulhi((unsigned)i, M)) + y1) * NW
                                             + x1 + (i - ((w == 1) ? i : (int)__umulhi((unsigned)i, M)) * w)]);

    // 64-lane shuffle argmax reduce; tie -> smaller flat index (argmax semantics)
    for (int off = 32; off >= 1; off >>= 1) {
        const float ov = __shfl_down(best, off);
        const int   oi = __shfl_down(bidx, off);
        if (ov > best || (ov == best && oi < bidx)) { best = ov; bidx = oi; }
    }

    if (lane == 0) {
        const int col = bidx & (NW - 1);
        const int row = bidx >> 7;
        float conf = best;
        if (conf < KP_CONF) conf = 0.0f;
        kout[0] = (float)col / sx;
        kout[1] = (float)row / sy;
        kout[2] = conf;
    }
}

extern "C" void kernel_launch(void* const* d_in, const int* in_sizes, int n_in,
                              void* d_out, int out_size, void* d_ws, size_t ws_size,
                              hipStream_t stream) {
    const float* logits = (const float*)d_in[0];   // [4,100,2]
    const float* pboxes = (const float*)d_in[1];   // [4,100,4]
    const float* hm     = (const float*)d_in[2];   // [4,17,128,128]
    const int*   img_h  = (const int*)d_in[3];
    const int*   img_w  = (const int*)d_in[4];
    float* out = (float*)d_out;

    int* wkeep = (int*)d_ws;               // [400]
    int* wbox  = wkeep + NB * NQ;          // [1600]

    score_nms_kernel<<<NB, 128, 0, stream>>>(logits, pboxes, img_h, img_w, out, wkeep, wbox);
    kps_kernel<<<NB * NQ * NK, 64, 0, stream>>>(hm, wkeep, wbox, img_h, img_w, out);
}

// Round 4
// 110.417 us; speedup vs baseline: 2.8752x; 1.0019x over previous
//
#include <hip/hip_runtime.h>
#include <cmath>
#include <cfloat>

// Problem constants (fixed by setup_inputs: B=4, Q=100, K=17, H=W=128).
constexpr int NB = 4;
constexpr int NQ = 100;
constexpr int NK = 17;
constexpr int NH = 128;
constexpr int NW = 128;

constexpr float HUMAN_CONF = 0.7f;
constexpr float KP_CONF    = 0.5f;
constexpr float NMS_THR    = 0.5f;

// Output layout (flat float32, reference return order):
//   scores  [NB*NQ]          offset 0
//   boxes   [NB*NQ*4]        offset NB*NQ
//   kps     [NB*NQ*NK*3]     offset NB*NQ*5
//   keep    [NB*NQ]          offset NB*NQ*5 + NB*NQ*NK*3
constexpr int OFF_BOXES = NB * NQ;
constexpr int OFF_KPS   = NB * NQ * 5;
constexpr int OFF_KEEP  = NB * NQ * 5 + NB * NQ * NK * 3;

// ---------------- Kernel A: scores + boxes + NMS + compact live-ROI list ----------------
// One block per batch, 128 threads (2 waves). Also zero-fills this batch's kps
// slice (kernel B overwrites live entries only) and emits a compacted list of
// kept boxes with non-empty heatmap ROIs.
__global__ __launch_bounds__(128) void score_nms_kernel(
    const float* __restrict__ logits,   // [NB,NQ,2]
    const float* __restrict__ pboxes,   // [NB,NQ,4] cxcywh in [0,1]
    const int* __restrict__ img_h_p,    // scalar
    const int* __restrict__ img_w_p,    // scalar
    float* __restrict__ out,            // 22800 floats
    int* __restrict__ wcount,           // ws: [NB] live count per batch
    int2* __restrict__ wlist)           // ws: [NB*NQ] (packed x1|y1<<8|x2<<16|y2<<24, gi)
{
    const int b = blockIdx.x;
    const int t = threadIdx.x;

    __shared__ float sbx[NQ][4];          // xyxy image coords, original order
    __shared__ float ssc[NQ];             // softmax max prob
    __shared__ unsigned char sval[NQ];    // valid flag
    __shared__ int   sorder[NQ];          // sorted pos -> original idx
    __shared__ float sortb[NQ][4];        // boxes in sorted order
    __shared__ float sarea[NQ];
    __shared__ unsigned char ssv[NQ];     // valid in sorted order
    __shared__ unsigned long long smask0[NQ], smask1[NQ]; // IoU>thr bitmask per sorted row
    __shared__ unsigned long long skmask[2];              // keep bits (sorted positions)
    __shared__ unsigned long long swl0;                   // wave-0 live ballot

    // Zero-fill this batch's kps slice (NQ*NK*3 = 5100 floats). Independent
    // stores, fully overlapped with the compute below by the scheduler.
    {
        float* kz = out + OFF_KPS + b * (NQ * NK * 3);
        for (int i = t; i < NQ * NK * 3; i += 128) kz[i] = 0.0f;
    }

    const float iw = (float)img_w_p[0];
    const float ih = (float)img_h_p[0];
    const float sx = (float)NW / iw;      // 0.25 exact for 512
    const float sy = (float)NH / ih;

    if (t < NQ) {
        // softmax over 2 classes; score = max prob, label==0 iff l0 >= l1
        const float l0 = logits[(b * NQ + t) * 2 + 0];
        const float l1 = logits[(b * NQ + t) * 2 + 1];
        const float m  = fmaxf(l0, l1);
        const float e0 = expf(l0 - m);
        const float e1 = expf(l1 - m);
        const float score = fmaxf(e0, e1) / (e0 + e1);
        const bool  lab0  = (l0 >= l1);

        const float cx = pboxes[(b * NQ + t) * 4 + 0];
        const float cy = pboxes[(b * NQ + t) * 4 + 1];
        const float w  = pboxes[(b * NQ + t) * 4 + 2];
        const float h  = pboxes[(b * NQ + t) * 4 + 3];
        sbx[t][0] = (cx - 0.5f * w) * iw;
        sbx[t][1] = (cy - 0.5f * h) * ih;
        sbx[t][2] = (cx + 0.5f * w) * iw;
        sbx[t][3] = (cy + 0.5f * h) * ih;
        ssc[t]  = score;
        sval[t] = (lab0 && score >= HUMAN_CONF) ? 1 : 0;
    }
    __syncthreads();

    // Rank by (key desc, index desc) == reverse of stable ascending argsort.
    if (t < NQ) {
        const float key = sval[t] ? ssc[t] : -INFINITY;
        int rank = 0;
        for (int j = 0; j < NQ; ++j) {
            const float kj = sval[j] ? ssc[j] : -INFINITY;
            if (kj > key || (kj == key && j > t)) rank++;
        }
        sorder[rank] = t;
    }
    __syncthreads();

    if (t < NQ) {
        const int oi = sorder[t];
        const float x1 = sbx[oi][0], y1 = sbx[oi][1], x2 = sbx[oi][2], y2 = sbx[oi][3];
        sortb[t][0] = x1; sortb[t][1] = y1; sortb[t][2] = x2; sortb[t][3] = y2;
        sarea[t] = fmaxf(x2 - x1, 0.0f) * fmaxf(y2 - y1, 0.0f);
        ssv[t]   = sval[oi];
    }
    __syncthreads();

    // Each sorted row t: bitmask over columns j with IoU(t,j) > thr.
    if (t < NQ) {
        unsigned long long m0 = 0ull, m1 = 0ull;
        const float ax1 = sortb[t][0], ay1 = sortb[t][1], ax2 = sortb[t][2], ay2 = sortb[t][3];
        const float aa = sarea[t];
        for (int j = 0; j < NQ; ++j) {
            const float lx = fmaxf(ax1, sortb[j][0]);
            const float ly = fmaxf(ay1, sortb[j][1]);
            const float rx = fminf(ax2, sortb[j][2]);
            const float ry = fminf(ay2, sortb[j][3]);
            const float wv = fmaxf(rx - lx, 0.0f);
            const float hv = fmaxf(ry - ly, 0.0f);
            const float inter = wv * hv;
            const float uni = aa + sarea[j] - inter;
            const float iou = inter / fmaxf(uni, 1e-9f);
            if (iou > NMS_THR) {
                if (j < 64) m0 |= 1ull << j; else m1 |= 1ull << (j - 64);
            }
        }
        smask0[t] = m0; smask1[t] = m1;
    }
    __syncthreads();

    // Serial greedy over bitmasks (thread 0). Sorted order puts all valid
    // boxes first, so break at the first invalid position.
    if (t == 0) {
        unsigned long long sup0 = 0ull, sup1 = 0ull, k0 = 0ull, k1 = 0ull;
        for (int i = 0; i < NQ; ++i) {
            if (!ssv[i]) break;
            const bool sup = (i < 64) ? ((sup0 >> i) & 1ull) : ((sup1 >> (i - 64)) & 1ull);
            if (!sup) {
                if (i < 64) k0 |= 1ull << i; else k1 |= 1ull << (i - 64);
                sup0 |= smask0[i];
                sup1 |= smask1[i];
            }
        }
        skmask[0] = k0; skmask[1] = k1;
    }
    __syncthreads();

    // Write scores/boxes/keep outputs + compact live list.
    int  kp = 0, gi = 0;
    int  x1i = 0, y1i = 0, x2i = 0, y2i = 0;
    bool live = false;

    if (t < NQ) {
        const int oi = sorder[t];
        kp = (t < 64) ? (int)((skmask[0] >> t) & 1ull)
                      : (int)((skmask[1] >> (t - 64)) & 1ull);
        gi = b * NQ + oi;

        out[gi] = ssc[oi] * (float)kp;

        const int bi0 = (int)sbx[oi][0];   // trunc toward zero == astype(int32)
        const int bi1 = (int)sbx[oi][1];
        const int bi2 = (int)sbx[oi][2];
        const int bi3 = (int)sbx[oi][3];
        out[OFF_BOXES + gi * 4 + 0] = (float)(bi0 * kp);
        out[OFF_BOXES + gi * 4 + 1] = (float)(bi1 * kp);
        out[OFF_BOXES + gi * 4 + 2] = (float)(bi2 * kp);
        out[OFF_BOXES + gi * 4 + 3] = (float)(bi3 * kp);

        out[OFF_KEEP + gi] = (float)kp;

        // ROI bounds: int * 0.25f exact; trunc toward zero matches astype(int32).
        x1i = max((int)((float)bi0 * sx), 0);
        y1i = max((int)((float)bi1 * sy), 0);
        x2i = min((int)((float)bi2 * sx) + 1, NW);
        y2i = min((int)((float)bi3 * sy) + 1, NH);
        live = kp && (x2i > x1i) && (y2i > y1i);   // empty-ROI kept boxes stay zero
    }

    // Compact live entries: rank = #live threads with smaller t (2-wave prefix).
    const unsigned long long lm = __ballot(live);
    if (t == 0) swl0 = lm;
    __syncthreads();
    if (t == 64) wcount[b] = __popcll(swl0) + __popcll(lm);
    const int lane = t & 63;
    const unsigned long long below = lm & ((lane ? (1ull << lane) : 1ull) - 1ull);
    const int rank = (t < 64) ? __popcll(below) : __popcll(swl0) + __popcll(below);
    if (live) {
        const int pack = x1i | (y1i << 8) | (x2i << 16) | (y2i << 24);  // all in [0,128]
        wlist[b * NQ + rank] = make_int2(pack, gi);
    }
}

// ---------------- Kernel B: ROI keypoint argmax, one wave per (live box, keypoint) ----------------
// Grid = NB*NQ*NK blocks of 64 threads. Block (b, r, k): if r >= wcount[b] the
// block exits after one L2-hot scalar load (kps already zeroed by kernel A).
// Live blocks scan the ROI as aligned float4 chunks, 4 loads in flight.
__global__ __launch_bounds__(64) void kps_kernel(
    const float* __restrict__ hm,       // [NB,NK,NH,NW]
    const int* __restrict__ wcount,     // [NB]
    const int2* __restrict__ wlist,     // [NB*NQ]
    const int* __restrict__ img_h_p,
    const int* __restrict__ img_w_p,
    float* __restrict__ out)
{
    const int bb  = blockIdx.x;               // b*(NQ*NK) + r*NK + k
    const int b   = bb / (NQ * NK);
    const int rem = bb - b * (NQ * NK);
    const int r   = rem / NK;
    const int k   = rem - r * NK;

    if (r >= wcount[b]) return;               // dead block: nothing to do

    const int2 wl = wlist[b * NQ + r];
    const int x1 = wl.x & 255;
    const int y1 = (wl.x >> 8) & 255;
    const int x2 = (wl.x >> 16) & 255;
    const int y2 = (wl.x >> 24) & 255;
    const int gi = wl.y;

    const int lane = threadIdx.x;
    const float sx = (float)NW / (float)img_w_p[0];
    const float sy = (float)NH / (float)img_h_p[0];

    const float4* __restrict__ b4 =
        (const float4*)(hm + (size_t)(b * NK + k) * (NH * NW));   // 64KB-aligned

    const int xa     = x1 & ~3;                     // align ROI left edge down
    const int C4     = (x2 - xa + 3) >> 2;          // float4 chunks per row, 1..32
    const int R      = y2 - y1;
    const int total4 = R * C4;                      // < 2^12
    const unsigned M = (C4 > 1) ? (0xFFFFFFFFu / (unsigned)C4 + 1u) : 0u;

    float best = -INFINITY;
    int   bidx = 0x7fffffff;                        // global flat idx y*NW+x

    auto proc = [&](int idx, float4 v) {
        const int row = (C4 == 1) ? idx : (int)__umulhi((unsigned)idx, M);
        const int xb  = xa + (idx - row * C4) * 4;
        const int g   = (y1 + row) * NW + xb;
        // component order = increasing x = increasing flat idx; strict > keeps
        // the earliest occurrence (argmax tie semantics)
        const float v0 = (xb + 0 >= x1 && xb + 0 < x2) ? v.x : -INFINITY;
        const float v1 = (xb + 1 >= x1 && xb + 1 < x2) ? v.y : -INFINITY;
        const float v2 = (xb + 2 >= x1 && xb + 2 < x2) ? v.z : -INFINITY;
        const float v3 = (xb + 3 < x2) ? v.w : -INFINITY;
        if (v0 > best) { best = v0; bidx = g + 0; }
        if (v1 > best) { best = v1; bidx = g + 1; }
        if (v2 > best) { best = v2; bidx = g + 2; }
        if (v3 > best) { best = v3; bidx = g + 3; }
    };
    auto caddr = [&](int idx) {
        const int row = (C4 == 1) ? idx : (int)__umulhi((unsigned)idx, M);
        return (y1 + row) * (NW / 4) + (xa >> 2) + (idx - row * C4);
    };

    int idx = lane;
    // 4 chunk-loads in flight per iteration (16 values).
    for (; idx + 192 < total4; idx += 256) {
        const int a0 = caddr(idx), a1 = caddr(idx + 64), a2 = caddr(idx + 128), a3 = caddr(idx + 192);
        const float4 v0 = b4[a0];
        const float4 v1 = b4[a1];
        const float4 v2 = b4[a2];
        const float4 v3 = b4[a3];
        proc(idx, v0);
        proc(idx + 64, v1);
        proc(idx + 128, v2);
        proc(idx + 192, v3);
    }
    for (; idx < total4; idx += 64) proc(idx, b4[caddr(idx)]);

    // 64-lane shuffle argmax reduce; tie -> smaller flat index (argmax semantics)
    for (int off = 32; off >= 1; off >>= 1) {
        const float ov = __shfl_down(best, off);
        const int   oi = __shfl_down(bidx, off);
        if (ov > best || (ov == best && oi < bidx)) { best = ov; bidx = oi; }
    }

    if (lane == 0) {
        const int col = bidx & (NW - 1);
        const int row = bidx >> 7;
        float conf = best;
        if (conf < KP_CONF) conf = 0.0f;
        float* kout = out + OFF_KPS + (size_t)gi * (NK * 3) + k * 3;
        kout[0] = (float)col / sx;
        kout[1] = (float)row / sy;
        kout[2] = conf;
    }
}

extern "C" void kernel_launch(void* const* d_in, const int* in_sizes, int n_in,
                              void* d_out, int out_size, void* d_ws, size_t ws_size,
                              hipStream_t stream) {
    const float* logits = (const float*)d_in[0];   // [4,100,2]
    const float* pboxes = (const float*)d_in[1];   // [4,100,4]
    const float* hm     = (const float*)d_in[2];   // [4,17,128,128]
    const int*   img_h  = (const int*)d_in[3];
    const int*   img_w  = (const int*)d_in[4];
    float* out = (float*)d_out;

    int*  wcount = (int*)d_ws;                 // [4]
    int2* wlist  = (int2*)((char*)d_ws + 256); // [400], aligned

    score_nms_kernel<<<NB, 128, 0, stream>>>(logits, pboxes, img_h, img_w, out, wcount, wlist);
    kps_kernel<<<NB * NQ * NK, 64, 0, stream>>>(hm, wcount, wlist, img_h, img_w, out);
}